// Round 9
// baseline (616.834 us; speedup 1.0000x reference)
//
#include <hip/hip_runtime.h>
#include <hip/hip_bf16.h>

#define DIM 128
#define GATE_EPS 1e-6f
#define BN_EPS 1e-5f

typedef unsigned int u32;
typedef unsigned short u16;

typedef __attribute__((ext_vector_type(8))) short short8v;  // 8 bf16 (bitcast ok)
typedef __attribute__((ext_vector_type(4))) float f32x4;

__device__ __forceinline__ float bflo(u32 u) { return __uint_as_float(u << 16); }
__device__ __forceinline__ float bfhi(u32 u) { return __uint_as_float(u & 0xffff0000u); }

__device__ __forceinline__ u16 f2bf(float f) {
    u32 u = __float_as_uint(f);
    u32 r = (u + 0x7fffu + ((u >> 16) & 1u)) >> 16;  // RNE
    return (u16)r;
}

__device__ __forceinline__ float bf2f(u16 v) {
    return __uint_as_float(((u32)v) << 16);
}

// scalar dtype-adaptive load
__device__ __forceinline__ float loadF(const void* p, size_t i, int bf) {
    if (bf) return __uint_as_float(((u32)((const u16*)p)[i]) << 16);
    return ((const float*)p)[i];
}

// ---------------------------------------------------------------------------
// K0: detect device float dtype (verbatim from passing rounds).
// ---------------------------------------------------------------------------
__global__ void detect_dtype(const void* __restrict__ h, int* __restrict__ flag) {
    if (threadIdx.x == 0 && blockIdx.x == 0) {
        const u16* us = (const u16*)h;
        int cnt = 0;
        for (int i = 0; i < 256; ++i) {
            int e8 = (us[2 * i] >> 7) & 0xFF;
            if (e8 >= 0x60 && e8 <= 0x8F) ++cnt;
        }
        *flag = (cnt >= 192) ? 1 : 0;
    }
}

// ---------------------------------------------------------------------------
// W transpose prep for MFMA B-fragments: Wt[p][c][k] = W_p[k][c].
// ---------------------------------------------------------------------------
__global__ __launch_bounds__(256) void k_transposeW(
    const u16* __restrict__ W0, const u16* __restrict__ W1,
    const u16* __restrict__ W2, const u16* __restrict__ W3,
    u32* __restrict__ Wt32)   // [4][128][64] u32
{
    int p = blockIdx.x;
    const u16* W = (p == 0) ? W0 : (p == 1) ? W1 : (p == 2) ? W2 : W3;
    int t = threadIdx.x;
    for (int i = t; i < 8192; i += 256) {
        int c = i >> 6;
        int g = i & 63;
        u16 lo = W[(2 * g) * DIM + c];
        u16 hi = W[(2 * g + 1) * DIM + c];
        Wt32[p * 8192 + i] = (u32)lo | ((u32)hi << 16);
    }
}

// ---------------------------------------------------------------------------
// K1a: MFMA projection GEMM (under test; k_verify+k_repair guard it).
// grid=(ceil(N/64), 8): proj=y>>1, colhalf=y&1. 4 waves; wave=16 rows x 64 cols.
// ---------------------------------------------------------------------------
__global__ __launch_bounds__(256) void mfma_proj(
    const u16* __restrict__ h, const u16* __restrict__ Wt,
    const u16* __restrict__ b0, const u16* __restrict__ b1,
    const u16* __restrict__ b2, const u16* __restrict__ b3,
    float* __restrict__ Ah, u16* __restrict__ DBu, u16* __restrict__ Ehbu,
    int N)
{
    const int p  = blockIdx.y >> 1;
    const int ch = blockIdx.y & 1;
    const u16* bias = (p == 0) ? b0 : (p == 1) ? b1 : (p == 2) ? b2 : b3;

    const int t = threadIdx.x;
    const int l = t & 63;
    const int w = t >> 6;
    const int m0 = blockIdx.x * 64 + w * 16;

    int row_a = m0 + (l & 15);
    int rowc = (row_a < N) ? row_a : (N - 1);
    const u16* hp = h + (size_t)rowc * DIM + ((l >> 4) * 8);
    short8v a0 = *(const short8v*)(hp + 0);
    short8v a1 = *(const short8v*)(hp + 32);
    short8v a2 = *(const short8v*)(hp + 64);
    short8v a3 = *(const short8v*)(hp + 96);

    const int ln16 = l & 15;
    const int kgrp = (l >> 4) * 8;

    #pragma unroll
    for (int ct = 0; ct < 4; ++ct) {
        const int ccol = ch * 64 + ct * 16 + ln16;
        const u16* wp = Wt + ((size_t)(p * DIM + ccol)) * DIM + kgrp;
        short8v q0 = *(const short8v*)(wp + 0);
        short8v q1 = *(const short8v*)(wp + 32);
        short8v q2 = *(const short8v*)(wp + 64);
        short8v q3 = *(const short8v*)(wp + 96);

        f32x4 acc = {0.f, 0.f, 0.f, 0.f};
        acc = __builtin_amdgcn_mfma_f32_16x16x32_bf16(a0, q0, acc, 0, 0, 0);
        acc = __builtin_amdgcn_mfma_f32_16x16x32_bf16(a1, q1, acc, 0, 0, 0);
        acc = __builtin_amdgcn_mfma_f32_16x16x32_bf16(a2, q2, acc, 0, 0, 0);
        acc = __builtin_amdgcn_mfma_f32_16x16x32_bf16(a3, q3, acc, 0, 0, 0);

        float bv = bf2f(bias[ccol]);

        #pragma unroll
        for (int r = 0; r < 4; ++r) {
            int row = m0 + (l >> 4) * 4 + r;
            if (row < N) {
                float v = acc[r] + bv;
                if (p == 0)      Ah[(size_t)row * DIM + ccol] = v;
                else if (p == 1) DBu[(size_t)row * 256 + 128 + ccol] = f2bf(v);
                else if (p == 2) DBu[(size_t)row * 256 + ccol] = f2bf(v);
                else             Ehbu[(size_t)row * DIM + ccol] = f2bf(v);
            }
        }
    }
}

// ---------------------------------------------------------------------------
// K1b: verify 512 scattered samples of mfma_proj's output against a direct
// f32 recompute from raw h/W. Writes okp[0] = 1 iff all within tol.
// ---------------------------------------------------------------------------
__global__ __launch_bounds__(256) void k_verify(
    const u16* __restrict__ h,
    const u16* __restrict__ Wa, const u16* __restrict__ Wb,
    const u16* __restrict__ Wd, const u16* __restrict__ We,
    const u16* __restrict__ ba, const u16* __restrict__ bb,
    const u16* __restrict__ bd, const u16* __restrict__ be,
    const float* __restrict__ Ah, const u16* __restrict__ DBu,
    const u16* __restrict__ Ehbu,
    int N, int* __restrict__ okp)
{
    __shared__ int nbad;
    int t = threadIdx.x;
    if (t == 0) nbad = 0;
    __syncthreads();
    for (int s = 0; s < 2; ++s) {
        int idx = t + s * 256;
        int p = idx & 3;
        int r = (int)(((long long)idx * 1999 + 17) % N);
        int c = (idx * 37 + 5) & 127;
        const u16* W  = (p == 0) ? Wa : (p == 1) ? Wb : (p == 2) ? Wd : We;
        const u16* bi = (p == 0) ? ba : (p == 1) ? bb : (p == 2) ? bd : be;
        float acc = 0.f;
        for (int k = 0; k < DIM; ++k)
            acc += bf2f(h[(size_t)r * DIM + k]) * bf2f(W[(size_t)k * DIM + c]);
        acc += bf2f(bi[c]);
        float got;
        if (p == 0)      got = Ah[(size_t)r * DIM + c];
        else if (p == 1) got = bf2f(DBu[(size_t)r * 256 + 128 + c]);
        else if (p == 2) got = bf2f(DBu[(size_t)r * 256 + c]);
        else             got = bf2f(Ehbu[(size_t)r * DIM + c]);
        if (fabsf(got - acc) > 0.08f) atomicAdd(&nbad, 1);
    }
    __syncthreads();
    if (t == 0) okp[0] = (nbad == 0) ? 1 : 0;
}

// ---------------------------------------------------------------------------
// K1c: repair = R7's verbatim VALU proj_gemm with uniform early-exit when
// the MFMA output verified OK. Guarantees correctness either way.
// ---------------------------------------------------------------------------
__global__ __launch_bounds__(256) void k_repair(
    const void* __restrict__ h,
    const void* __restrict__ W0, const void* __restrict__ b0,
    const void* __restrict__ W1, const void* __restrict__ b1,
    const void* __restrict__ W2, const void* __restrict__ b2,
    const void* __restrict__ W3, const void* __restrict__ b3,
    float* __restrict__ oAh, u32* __restrict__ oDB, u32* __restrict__ oEhb,
    int N, const int* __restrict__ flagp, const int* __restrict__ okp)
{
    if (okp[0]) return;   // MFMA verified -> nothing to do

    const void* W; const void* bias;
    switch (blockIdx.y) {
        case 0:  W = W0; bias = b0; break;
        case 1:  W = W1; bias = b1; break;
        case 2:  W = W2; bias = b2; break;
        default: W = W3; bias = b3; break;
    }
    const int bf = *flagp;

    __shared__ float Hs[64][DIM + 4];
    __shared__ float Ws[16][DIM];

    const int t  = threadIdx.x;
    const int m0 = blockIdx.x * 64;

    if (bf) {
        for (int f = t; f < 1024; f += 256) {
            int r = f >> 4, c8 = f & 15;
            int gr = m0 + r;
            uint4 v = make_uint4(0u, 0u, 0u, 0u);
            if (gr < N) v = ((const uint4*)h)[(size_t)gr * 16 + c8];
            float* p = &Hs[r][c8 * 8];
            p[0] = bflo(v.x); p[1] = bfhi(v.x);
            p[2] = bflo(v.y); p[3] = bfhi(v.y);
            p[4] = bflo(v.z); p[5] = bfhi(v.z);
            p[6] = bflo(v.w); p[7] = bfhi(v.w);
        }
    } else {
        for (int f = t; f < 2048; f += 256) {
            int r = f >> 5, c4 = f & 31;
            int gr = m0 + r;
            float4 v = make_float4(0.f, 0.f, 0.f, 0.f);
            if (gr < N) v = ((const float4*)h)[(size_t)gr * 32 + c4];
            float* p = &Hs[r][c4 * 4];
            p[0] = v.x; p[1] = v.y; p[2] = v.z; p[3] = v.w;
        }
    }

    const int cg = t & 31;
    const int rg = t >> 5;

    float acc[8][4];
    #pragma unroll
    for (int i = 0; i < 8; ++i)
        #pragma unroll
        for (int j = 0; j < 4; ++j) acc[i][j] = 0.f;

    for (int kc = 0; kc < DIM; kc += 16) {
        __syncthreads();
        if (bf) {
            int r = t >> 4, c8 = t & 15;
            uint4 v = ((const uint4*)W)[(size_t)(kc + r) * 16 + c8];
            float* p = &Ws[r][c8 * 8];
            p[0] = bflo(v.x); p[1] = bfhi(v.x);
            p[2] = bflo(v.y); p[3] = bfhi(v.y);
            p[4] = bflo(v.z); p[5] = bfhi(v.z);
            p[6] = bflo(v.w); p[7] = bfhi(v.w);
        } else {
            for (int f = t; f < 512; f += 256) {
                int r = f >> 5, c4 = f & 31;
                float4 v = ((const float4*)W)[(size_t)(kc + r) * 32 + c4];
                float* p = &Ws[r][c4 * 4];
                p[0] = v.x; p[1] = v.y; p[2] = v.z; p[3] = v.w;
            }
        }
        __syncthreads();
        #pragma unroll
        for (int kk = 0; kk < 16; ++kk) {
            float4 w = *((const float4*)&Ws[kk][cg * 4]);
            #pragma unroll
            for (int i = 0; i < 8; ++i) {
                float hv = Hs[rg * 8 + i][kc + kk];
                acc[i][0] += hv * w.x;
                acc[i][1] += hv * w.y;
                acc[i][2] += hv * w.z;
                acc[i][3] += hv * w.w;
            }
        }
    }

    float bv[4];
    #pragma unroll
    for (int j = 0; j < 4; ++j) bv[j] = loadF(bias, cg * 4 + j, bf);

    const int y = blockIdx.y;
    #pragma unroll
    for (int i = 0; i < 8; ++i) {
        int gr = m0 + rg * 8 + i;
        if (gr < N) {
            float v0 = acc[i][0] + bv[0];
            float v1 = acc[i][1] + bv[1];
            float v2 = acc[i][2] + bv[2];
            float v3 = acc[i][3] + bv[3];
            if (y == 0) {
                ((float4*)oAh)[(size_t)gr * 32 + cg] = make_float4(v0, v1, v2, v3);
            } else {
                uint2 p;
                p.x = (u32)f2bf(v0) | ((u32)f2bf(v1) << 16);
                p.y = (u32)f2bf(v2) | ((u32)f2bf(v3) << 16);
                size_t idx;
                if (y == 1)      idx = (size_t)gr * 64 + 32 + cg;
                else if (y == 2) idx = (size_t)gr * 64 + cg;
                else             idx = (size_t)gr * 32 + cg;
                u32* base = (y == 3) ? oEhb : oDB;
                ((uint2*)base)[idx] = p;
            }
        }
    }
}

// ---------------------------------------------------------------------------
// CSR build (verbatim from passing rounds).
// ---------------------------------------------------------------------------
__global__ __launch_bounds__(256) void k_hist(const int* __restrict__ dst,
                                              int* __restrict__ deg, int E)
{
    int e = blockIdx.x * 256 + threadIdx.x;
    if (e < E) atomicAdd(&deg[dst[e]], 1);
}

__global__ __launch_bounds__(256) void k_scan1(const int* __restrict__ deg,
                                               int* __restrict__ rowstart,
                                               int* __restrict__ part, int N)
{
    __shared__ int s[256];
    int t = threadIdx.x;
    int i = blockIdx.x * 256 + t;
    int d = (i < N) ? deg[i] : 0;
    s[t] = d;
    __syncthreads();
    for (int off = 1; off < 256; off <<= 1) {
        int v = (t >= off) ? s[t - off] : 0;
        __syncthreads();
        s[t] += v;
        __syncthreads();
    }
    if (i < N) rowstart[i] = s[t] - d;
    if (t == 255) part[blockIdx.x] = s[255];
}

__global__ void k_scan2(int* __restrict__ part, int nb)
{
    __shared__ int s[256];
    int t = threadIdx.x;
    int d = (t < nb) ? part[t] : 0;
    s[t] = d;
    __syncthreads();
    for (int off = 1; off < 256; off <<= 1) {
        int v = (t >= off) ? s[t - off] : 0;
        __syncthreads();
        s[t] += v;
        __syncthreads();
    }
    if (t < nb) part[t] = s[t] - d;
}

__global__ __launch_bounds__(256) void k_scan3(int* __restrict__ rowstart,
                                               int* __restrict__ cursor,
                                               const int* __restrict__ part,
                                               int N, int E)
{
    int i = blockIdx.x * 256 + threadIdx.x;
    if (i < N) {
        int v = rowstart[i] + part[blockIdx.x];
        rowstart[i] = v;
        cursor[i] = v;
    }
    if (i == 0) rowstart[N] = E;
}

__global__ __launch_bounds__(256) void k_scatter(const int* __restrict__ src,
                                                 const int* __restrict__ dst,
                                                 int* __restrict__ cursor,
                                                 int* __restrict__ esrc, int E)
{
    int e = blockIdx.x * 256 + threadIdx.x;
    if (e < E) {
        int pos = atomicAdd(&cursor[dst[e]], 1);
        esrc[pos] = src[e];
    }
}

// ---------------------------------------------------------------------------
// K3: CSR aggregation (verbatim from passing round 7: unroll x2).
// ---------------------------------------------------------------------------
__global__ __launch_bounds__(256) void k_aggregate(
    const float* __restrict__ Ah, const u32* __restrict__ DB,
    const u32* __restrict__ Ehb,
    const int* __restrict__ rowstart, const int* __restrict__ esrc,
    float* __restrict__ hnew, float* __restrict__ gsum, float* __restrict__ gsq,
    int N)
{
    int t = threadIdx.x;
    int lane = t & 63;
    int wv = t >> 6;
    int nquads = (N + 3) >> 2;

    float lsum0 = 0.f, lsum1 = 0.f, lsq0 = 0.f, lsq1 = 0.f;
    for (int q = blockIdx.x; q < nquads; q += gridDim.x) {
        int n = q * 4 + wv;
        if (n < N) {
            u32 ehp = Ehb[(size_t)n * 64 + lane];
            float eh0 = bflo(ehp), eh1 = bfhi(ehp);
            float2 ahp = ((const float2*)Ah)[(size_t)n * 64 + lane];
            float num0 = 0.f, den0 = 0.f, num1 = 0.f, den1 = 0.f;
            int beg = rowstart[n], end = rowstart[n + 1];
            int k = beg;
            for (; k + 2 <= end; k += 2) {
                int s0 = esrc[k], s1 = esrc[k + 1];
                u32 dh0 = DB[(size_t)s0 * 128 + lane];
                u32 bh0 = DB[(size_t)s0 * 128 + 64 + lane];
                u32 dh1 = DB[(size_t)s1 * 128 + lane];
                u32 bh1 = DB[(size_t)s1 * 128 + 64 + lane];
                float sa0 = 1.f / (1.f + __expf(-(bflo(dh0) + eh0)));
                float sa1 = 1.f / (1.f + __expf(-(bfhi(dh0) + eh1)));
                float sb0 = 1.f / (1.f + __expf(-(bflo(dh1) + eh0)));
                float sb1 = 1.f / (1.f + __expf(-(bfhi(dh1) + eh1)));
                num0 = fmaf(sa0, bflo(bh0), num0); den0 += sa0;
                num1 = fmaf(sa1, bfhi(bh0), num1); den1 += sa1;
                num0 = fmaf(sb0, bflo(bh1), num0); den0 += sb0;
                num1 = fmaf(sb1, bfhi(bh1), num1); den1 += sb1;
            }
            if (k < end) {
                int s0 = esrc[k];
                u32 dh0 = DB[(size_t)s0 * 128 + lane];
                u32 bh0 = DB[(size_t)s0 * 128 + 64 + lane];
                float sa0 = 1.f / (1.f + __expf(-(bflo(dh0) + eh0)));
                float sa1 = 1.f / (1.f + __expf(-(bfhi(dh0) + eh1)));
                num0 = fmaf(sa0, bflo(bh0), num0); den0 += sa0;
                num1 = fmaf(sa1, bfhi(bh0), num1); den1 += sa1;
            }
            float x0 = ahp.x + num0 / (den0 + GATE_EPS);
            float x1 = ahp.y + num1 / (den1 + GATE_EPS);
            ((float2*)hnew)[(size_t)n * 64 + lane] = make_float2(x0, x1);
            lsum0 += x0; lsq0 += x0 * x0;
            lsum1 += x1; lsq1 += x1 * x1;
        }
    }
    __shared__ float S0[256], S1[256], Q0[256], Q1[256];
    S0[t] = lsum0; S1[t] = lsum1; Q0[t] = lsq0; Q1[t] = lsq1;
    __syncthreads();
    if (t < 64) {
        float s0 = S0[t] + S0[t + 64] + S0[t + 128] + S0[t + 192];
        float s1 = S1[t] + S1[t + 64] + S1[t + 128] + S1[t + 192];
        float q0 = Q0[t] + Q0[t + 64] + Q0[t + 128] + Q0[t + 192];
        float q1 = Q1[t] + Q1[t + 64] + Q1[t + 128] + Q1[t + 192];
        atomicAdd(&gsum[2 * t],     s0);
        atomicAdd(&gsum[2 * t + 1], s1);
        atomicAdd(&gsq[2 * t],      q0);
        atomicAdd(&gsq[2 * t + 1],  q1);
    }
}

// ---------------------------------------------------------------------------
// K4: finalize BN stats (verbatim from passing round 7).
// ---------------------------------------------------------------------------
__global__ void bn_finalize(const float* __restrict__ gsum, const float* __restrict__ gsq,
                            const void* __restrict__ gamma, const void* __restrict__ beta,
                            float* __restrict__ scale, float* __restrict__ shift,
                            int N, const int* __restrict__ flagp)
{
    int c = threadIdx.x;
    int bf = *flagp;
    if (c < DIM) {
        float invn = 1.f / (float)N;
        float mean = gsum[c] * invn;
        float var  = fmaxf(gsq[c] * invn - mean * mean, 0.f);
        float g = loadF(gamma, c, bf);
        float b = loadF(beta, c, bf);
        float sc = rsqrtf(var + BN_EPS) * g;
        scale[c] = sc;
        shift[c] = b - mean * sc;
    }
}

// ---------------------------------------------------------------------------
// K5: y = relu(x*scale + shift), scalar store (verbatim from passing rounds).
// ---------------------------------------------------------------------------
__global__ __launch_bounds__(256) void bn_apply(
    const float* __restrict__ hnew, const float* __restrict__ scale,
    const float* __restrict__ shift, void* __restrict__ outh,
    int total, const int* __restrict__ flagp)
{
    __shared__ float s_sc[DIM], s_sh[DIM];
    int t = threadIdx.x;
    if (t < DIM) { s_sc[t] = scale[t]; s_sh[t] = shift[t]; }
    __syncthreads();
    int bf = *flagp;

    int idx = blockIdx.x * 256 + t;
    int stride = gridDim.x * 256;
    for (int i = idx; i < total; i += stride) {
        int c = i & 127;
        float x = fmaxf(0.f, hnew[i] * s_sc[c] + s_sh[c]);
        if (bf) ((u16*)outh)[i] = f2bf(x);
        else    ((float*)outh)[i] = x;
    }
}

// ---------------------------------------------------------------------------
// K6: copy e into d_out at element offset nd (verbatim from passing rounds).
// ---------------------------------------------------------------------------
__global__ __launch_bounds__(256) void copy_e(
    const void* __restrict__ e, void* __restrict__ dout,
    size_t nd, size_t ecount, const int* __restrict__ flagp)
{
    int bf = *flagp;
    size_t esz = bf ? 2 : 4;
    const uint4* s = (const uint4*)e;
    uint4* d = (uint4*)((char*)dout + nd * esz);
    size_t n16 = (ecount * esz) / 16;
    size_t idx = (size_t)blockIdx.x * 256 + threadIdx.x;
    size_t stride = (size_t)gridDim.x * 256;
    for (size_t i = idx; i < n16; i += stride) d[i] = s[i];
}

// ---------------------------------------------------------------------------
extern "C" void kernel_launch(void* const* d_in, const int* in_sizes, int n_in,
                              void* d_out, int out_size, void* d_ws, size_t ws_size,
                              hipStream_t stream)
{
    const void* h     = d_in[0];
    const void* e     = d_in[1];
    const int*  src   = (const int*)d_in[2];
    const int*  dst   = (const int*)d_in[3];
    const void* Wa    = d_in[4];
    const void* ba    = d_in[5];
    const void* Wb    = d_in[6];
    const void* bb    = d_in[7];
    const void* Wd    = d_in[8];
    const void* bd    = d_in[9];
    const void* We    = d_in[10];
    const void* be    = d_in[11];
    const void* gamma = d_in[12];
    const void* beta  = d_in[13];

    const int N = in_sizes[0] / DIM;        // 50000
    const int E = in_sizes[2];              // 800000
    const size_t nd = (size_t)N * DIM;
    const size_t ecount = (size_t)E * DIM;

    float* ws    = (float*)d_ws;
    float* Ah    = ws;                         // nd f32
    float* hnew  = ws + nd;                    // nd f32
    u32*   DB    = (u32*)(ws + 2 * nd);        // N*128 u32 (Dh|Bh bf16 pairs)
    u32*   Ehb   = (u32*)(ws + 3 * nd);        // N*64 u32 (Eh bf16 pairs)
    float* gsum  = ws + 3 * nd + nd / 2;       // 128
    float* gsq   = gsum + DIM;                 // 128
    float* scale = gsum + 2 * DIM;             // 128
    float* shift = gsum + 3 * DIM;             // 128
    u32*   Wt32  = (u32*)(gsum + 4 * DIM);     // 4*8192 u32 = 128 KB
    int*   flag  = (int*)(Wt32 + 4 * 8192);    // [0]=dtype, [1]=mfma-ok
    int*   deg      = flag + 64;               // N
    int*   rowstart = deg + N;                 // N+1
    int*   cursor   = rowstart + N + 1;        // N
    int*   part     = cursor + N;              // 256
    int*   esrc     = part + 256;              // E

    detect_dtype<<<1, 64, 0, stream>>>(h, flag);

    // zero: BN stats + degree histogram
    hipMemsetAsync(gsum, 0, 4 * DIM * sizeof(float), stream);
    hipMemsetAsync(deg, 0, (size_t)N * sizeof(int), stream);

    const int nbE = (E + 255) / 256;
    const int nbN = (N + 255) / 256;

    k_hist<<<nbE, 256, 0, stream>>>(dst, deg, E);
    k_scan1<<<nbN, 256, 0, stream>>>(deg, rowstart, part, N);
    k_scan2<<<1, 256, 0, stream>>>(part, nbN);
    k_scan3<<<nbN, 256, 0, stream>>>(rowstart, cursor, part, N, E);
    k_scatter<<<nbE, 256, 0, stream>>>(src, dst, cursor, esrc, E);

    k_transposeW<<<4, 256, 0, stream>>>((const u16*)Wa, (const u16*)Wb,
                                        (const u16*)Wd, (const u16*)We, Wt32);

    dim3 gm((N + 63) / 64, 8);
    mfma_proj<<<gm, 256, 0, stream>>>((const u16*)h, (const u16*)Wt32,
                                      (const u16*)ba, (const u16*)bb,
                                      (const u16*)bd, (const u16*)be,
                                      Ah, (u16*)DB, (u16*)Ehb, N);

    k_verify<<<1, 256, 0, stream>>>((const u16*)h,
                                    (const u16*)Wa, (const u16*)Wb,
                                    (const u16*)Wd, (const u16*)We,
                                    (const u16*)ba, (const u16*)bb,
                                    (const u16*)bd, (const u16*)be,
                                    Ah, (const u16*)DB, (const u16*)Ehb,
                                    N, flag + 1);

    dim3 gr((N + 63) / 64, 4);
    k_repair<<<gr, 256, 0, stream>>>(h, Wa, ba, Wb, bb, Wd, bd, We, be,
                                     Ah, DB, Ehb, N, flag, flag + 1);

    k_aggregate<<<2048, 256, 0, stream>>>(Ah, DB, Ehb, rowstart, esrc,
                                          hnew, gsum, gsq, N);

    bn_finalize<<<1, 128, 0, stream>>>(gsum, gsq, gamma, beta, scale, shift, N, flag);

    bn_apply<<<2048, 256, 0, stream>>>(hnew, scale, shift, d_out, (int)nd, flag);

    copy_e<<<4096, 256, 0, stream>>>(e, d_out, nd, ecount, flag);
}

// Round 10
// 538.235 us; speedup vs baseline: 1.1460x; 1.1460x over previous
//
#include <hip/hip_runtime.h>
#include <hip/hip_bf16.h>

#define DIM 128
#define GATE_EPS 1e-6f
#define BN_EPS 1e-5f

typedef unsigned int u32;
typedef unsigned short u16;

typedef __attribute__((ext_vector_type(4))) short short4v;  // 4 bf16 = 2 VGPR
typedef __attribute__((ext_vector_type(4))) float f32x4;

#if __has_builtin(__builtin_amdgcn_mfma_f32_16x16x16bf16_1k)
#define HAVE_MFMA16 1
#define MFMA16(a, b, c) __builtin_amdgcn_mfma_f32_16x16x16bf16_1k((a), (b), (c), 0, 0, 0)
#else
#define HAVE_MFMA16 0
#endif

__device__ __forceinline__ float bflo(u32 u) { return __uint_as_float(u << 16); }
__device__ __forceinline__ float bfhi(u32 u) { return __uint_as_float(u & 0xffff0000u); }

__device__ __forceinline__ u16 f2bf(float f) {
    u32 u = __float_as_uint(f);
    u32 r = (u + 0x7fffu + ((u >> 16) & 1u)) >> 16;  // RNE
    return (u16)r;
}

__device__ __forceinline__ float bf2f(u16 v) {
    return __uint_as_float(((u32)v) << 16);
}

// scalar dtype-adaptive load
__device__ __forceinline__ float loadF(const void* p, size_t i, int bf) {
    if (bf) return __uint_as_float(((u32)((const u16*)p)[i]) << 16);
    return ((const float*)p)[i];
}

// ---------------------------------------------------------------------------
// K0: detect device float dtype (verbatim from passing rounds).
// ---------------------------------------------------------------------------
__global__ void detect_dtype(const void* __restrict__ h, int* __restrict__ flag) {
    if (threadIdx.x == 0 && blockIdx.x == 0) {
        const u16* us = (const u16*)h;
        int cnt = 0;
        for (int i = 0; i < 256; ++i) {
            int e8 = (us[2 * i] >> 7) & 0xFF;
            if (e8 >= 0x60 && e8 <= 0x8F) ++cnt;
        }
        *flag = (cnt >= 192) ? 1 : 0;
    }
}

// ---------------------------------------------------------------------------
// W transpose prep: Wt[p][c][k] = W_p[k][c] (verbatim from round 9).
// ---------------------------------------------------------------------------
__global__ __launch_bounds__(256) void k_transposeW(
    const u16* __restrict__ W0, const u16* __restrict__ W1,
    const u16* __restrict__ W2, const u16* __restrict__ W3,
    u32* __restrict__ Wt32)   // [4][128][64] u32
{
    int p = blockIdx.x;
    const u16* W = (p == 0) ? W0 : (p == 1) ? W1 : (p == 2) ? W2 : W3;
    int t = threadIdx.x;
    for (int i = t; i < 8192; i += 256) {
        int c = i >> 6;
        int g = i & 63;
        u16 lo = W[(2 * g) * DIM + c];
        u16 hi = W[(2 * g + 1) * DIM + c];
        Wt32[p * 8192 + i] = (u32)lo | ((u32)hi << 16);
    }
}

#if HAVE_MFMA16
// ---------------------------------------------------------------------------
// K1a: MFMA projection via CLASSIC 16x16x16 bf16 (lab-notes layouts, no K=32
// generalization). grid=(ceil(N/64), 8): proj=y>>1, colhalf=y&1. 4 waves;
// wave = 16 rows x 64 cols. A: lane l holds h[m0+(l&15)][16ks+4*(l>>4)+j];
// B: W[16ks+4*(l>>4)+j][ccol]; D: col=l&15, row=4*(l>>4)+r.
// Guarded by k_verify + k_repair.
// ---------------------------------------------------------------------------
__global__ __launch_bounds__(256) void mfma16_proj(
    const u16* __restrict__ h, const u16* __restrict__ Wt,
    const u16* __restrict__ b0, const u16* __restrict__ b1,
    const u16* __restrict__ b2, const u16* __restrict__ b3,
    float* __restrict__ Ah, u16* __restrict__ DBu, u16* __restrict__ Ehbu,
    int N)
{
    const int p  = blockIdx.y >> 1;
    const int ch = blockIdx.y & 1;
    const u16* bias = (p == 0) ? b0 : (p == 1) ? b1 : (p == 2) ? b2 : b3;

    const int t = threadIdx.x;
    const int l = t & 63;
    const int w = t >> 6;
    const int m0 = blockIdx.x * 64 + w * 16;

    int row_a = m0 + (l & 15);
    int rowc = (row_a < N) ? row_a : (N - 1);
    const u16* hp = h + (size_t)rowc * DIM + ((l >> 4) * 4);

    short4v A[8];
    #pragma unroll
    for (int ks = 0; ks < 8; ++ks)
        A[ks] = *(const short4v*)(hp + ks * 16);

    const int ln16 = l & 15;

    #pragma unroll
    for (int ct = 0; ct < 4; ++ct) {
        const int ccol = ch * 64 + ct * 16 + ln16;
        const u16* wp = Wt + ((size_t)(p * DIM + ccol)) * DIM + ((l >> 4) * 4);

        f32x4 acc = {0.f, 0.f, 0.f, 0.f};
        #pragma unroll
        for (int ks = 0; ks < 8; ++ks) {
            short4v B = *(const short4v*)(wp + ks * 16);
            acc = MFMA16(A[ks], B, acc);
        }

        float bv = bf2f(bias[ccol]);

        #pragma unroll
        for (int r = 0; r < 4; ++r) {
            int row = m0 + (l >> 4) * 4 + r;
            if (row < N) {
                float v = acc[r] + bv;
                if (p == 0)      Ah[(size_t)row * DIM + ccol] = v;
                else if (p == 1) DBu[(size_t)row * 256 + 128 + ccol] = f2bf(v);
                else if (p == 2) DBu[(size_t)row * 256 + ccol] = f2bf(v);
                else             Ehbu[(size_t)row * DIM + ccol] = f2bf(v);
            }
        }
    }
}
#endif

// ---------------------------------------------------------------------------
// K1b: verify 512 scattered samples vs f32 recompute (NaN-safe compare).
// ---------------------------------------------------------------------------
__global__ __launch_bounds__(256) void k_verify(
    const u16* __restrict__ h,
    const u16* __restrict__ Wa, const u16* __restrict__ Wb,
    const u16* __restrict__ Wd, const u16* __restrict__ We,
    const u16* __restrict__ ba, const u16* __restrict__ bb,
    const u16* __restrict__ bd, const u16* __restrict__ be,
    const float* __restrict__ Ah, const u16* __restrict__ DBu,
    const u16* __restrict__ Ehbu,
    int N, int* __restrict__ okp)
{
    __shared__ int nbad;
    int t = threadIdx.x;
    if (t == 0) nbad = 0;
    __syncthreads();
    for (int s = 0; s < 2; ++s) {
        int idx = t + s * 256;
        int p = idx & 3;
        int r = (int)(((long long)idx * 1999 + 17) % N);
        int c = (idx * 37 + 5) & 127;
        const u16* W  = (p == 0) ? Wa : (p == 1) ? Wb : (p == 2) ? Wd : We;
        const u16* bi = (p == 0) ? ba : (p == 1) ? bb : (p == 2) ? bd : be;
        float acc = 0.f;
        for (int k = 0; k < DIM; ++k)
            acc += bf2f(h[(size_t)r * DIM + k]) * bf2f(W[(size_t)k * DIM + c]);
        acc += bf2f(bi[c]);
        float got;
        if (p == 0)      got = Ah[(size_t)r * DIM + c];
        else if (p == 1) got = bf2f(DBu[(size_t)r * 256 + 128 + c]);
        else if (p == 2) got = bf2f(DBu[(size_t)r * 256 + c]);
        else             got = bf2f(Ehbu[(size_t)r * DIM + c]);
        if (!(fabsf(got - acc) <= 0.08f)) atomicAdd(&nbad, 1);  // NaN-safe
    }
    __syncthreads();
    if (t == 0) okp[0] = (nbad == 0) ? 1 : 0;
}

// ---------------------------------------------------------------------------
// K1c: repair = verbatim R7 VALU proj_gemm, uniform early-exit if verified OK.
// ---------------------------------------------------------------------------
__global__ __launch_bounds__(256) void k_repair(
    const void* __restrict__ h,
    const void* __restrict__ W0, const void* __restrict__ b0,
    const void* __restrict__ W1, const void* __restrict__ b1,
    const void* __restrict__ W2, const void* __restrict__ b2,
    const void* __restrict__ W3, const void* __restrict__ b3,
    float* __restrict__ oAh, u32* __restrict__ oDB, u32* __restrict__ oEhb,
    int N, const int* __restrict__ flagp, const int* __restrict__ okp)
{
    if (okp[0]) return;

    const void* W; const void* bias;
    switch (blockIdx.y) {
        case 0:  W = W0; bias = b0; break;
        case 1:  W = W1; bias = b1; break;
        case 2:  W = W2; bias = b2; break;
        default: W = W3; bias = b3; break;
    }
    const int bf = *flagp;

    __shared__ float Hs[64][DIM + 4];
    __shared__ float Ws[16][DIM];

    const int t  = threadIdx.x;
    const int m0 = blockIdx.x * 64;

    if (bf) {
        for (int f = t; f < 1024; f += 256) {
            int r = f >> 4, c8 = f & 15;
            int gr = m0 + r;
            uint4 v = make_uint4(0u, 0u, 0u, 0u);
            if (gr < N) v = ((const uint4*)h)[(size_t)gr * 16 + c8];
            float* p = &Hs[r][c8 * 8];
            p[0] = bflo(v.x); p[1] = bfhi(v.x);
            p[2] = bflo(v.y); p[3] = bfhi(v.y);
            p[4] = bflo(v.z); p[5] = bfhi(v.z);
            p[6] = bflo(v.w); p[7] = bfhi(v.w);
        }
    } else {
        for (int f = t; f < 2048; f += 256) {
            int r = f >> 5, c4 = f & 31;
            int gr = m0 + r;
            float4 v = make_float4(0.f, 0.f, 0.f, 0.f);
            if (gr < N) v = ((const float4*)h)[(size_t)gr * 32 + c4];
            float* p = &Hs[r][c4 * 4];
            p[0] = v.x; p[1] = v.y; p[2] = v.z; p[3] = v.w;
        }
    }

    const int cg = t & 31;
    const int rg = t >> 5;

    float acc[8][4];
    #pragma unroll
    for (int i = 0; i < 8; ++i)
        #pragma unroll
        for (int j = 0; j < 4; ++j) acc[i][j] = 0.f;

    for (int kc = 0; kc < DIM; kc += 16) {
        __syncthreads();
        if (bf) {
            int r = t >> 4, c8 = t & 15;
            uint4 v = ((const uint4*)W)[(size_t)(kc + r) * 16 + c8];
            float* p = &Ws[r][c8 * 8];
            p[0] = bflo(v.x); p[1] = bfhi(v.x);
            p[2] = bflo(v.y); p[3] = bfhi(v.y);
            p[4] = bflo(v.z); p[5] = bfhi(v.z);
            p[6] = bflo(v.w); p[7] = bfhi(v.w);
        } else {
            for (int f = t; f < 512; f += 256) {
                int r = f >> 5, c4 = f & 31;
                float4 v = ((const float4*)W)[(size_t)(kc + r) * 32 + c4];
                float* p = &Ws[r][c4 * 4];
                p[0] = v.x; p[1] = v.y; p[2] = v.z; p[3] = v.w;
            }
        }
        __syncthreads();
        #pragma unroll
        for (int kk = 0; kk < 16; ++kk) {
            float4 w = *((const float4*)&Ws[kk][cg * 4]);
            #pragma unroll
            for (int i = 0; i < 8; ++i) {
                float hv = Hs[rg * 8 + i][kc + kk];
                acc[i][0] += hv * w.x;
                acc[i][1] += hv * w.y;
                acc[i][2] += hv * w.z;
                acc[i][3] += hv * w.w;
            }
        }
    }

    float bv[4];
    #pragma unroll
    for (int j = 0; j < 4; ++j) bv[j] = loadF(bias, cg * 4 + j, bf);

    const int y = blockIdx.y;
    #pragma unroll
    for (int i = 0; i < 8; ++i) {
        int gr = m0 + rg * 8 + i;
        if (gr < N) {
            float v0 = acc[i][0] + bv[0];
            float v1 = acc[i][1] + bv[1];
            float v2 = acc[i][2] + bv[2];
            float v3 = acc[i][3] + bv[3];
            if (y == 0) {
                ((float4*)oAh)[(size_t)gr * 32 + cg] = make_float4(v0, v1, v2, v3);
            } else {
                uint2 p;
                p.x = (u32)f2bf(v0) | ((u32)f2bf(v1) << 16);
                p.y = (u32)f2bf(v2) | ((u32)f2bf(v3) << 16);
                size_t idx;
                if (y == 1)      idx = (size_t)gr * 64 + 32 + cg;
                else if (y == 2) idx = (size_t)gr * 64 + cg;
                else             idx = (size_t)gr * 32 + cg;
                u32* base = (y == 3) ? oEhb : oDB;
                ((uint2*)base)[idx] = p;
            }
        }
    }
}

// ---------------------------------------------------------------------------
// CSR build (verbatim from passing rounds).
// ---------------------------------------------------------------------------
__global__ __launch_bounds__(256) void k_hist(const int* __restrict__ dst,
                                              int* __restrict__ deg, int E)
{
    int e = blockIdx.x * 256 + threadIdx.x;
    if (e < E) atomicAdd(&deg[dst[e]], 1);
}

__global__ __launch_bounds__(256) void k_scan1(const int* __restrict__ deg,
                                               int* __restrict__ rowstart,
                                               int* __restrict__ part, int N)
{
    __shared__ int s[256];
    int t = threadIdx.x;
    int i = blockIdx.x * 256 + t;
    int d = (i < N) ? deg[i] : 0;
    s[t] = d;
    __syncthreads();
    for (int off = 1; off < 256; off <<= 1) {
        int v = (t >= off) ? s[t - off] : 0;
        __syncthreads();
        s[t] += v;
        __syncthreads();
    }
    if (i < N) rowstart[i] = s[t] - d;
    if (t == 255) part[blockIdx.x] = s[255];
}

__global__ void k_scan2(int* __restrict__ part, int nb)
{
    __shared__ int s[256];
    int t = threadIdx.x;
    int d = (t < nb) ? part[t] : 0;
    s[t] = d;
    __syncthreads();
    for (int off = 1; off < 256; off <<= 1) {
        int v = (t >= off) ? s[t - off] : 0;
        __syncthreads();
        s[t] += v;
        __syncthreads();
    }
    if (t < nb) part[t] = s[t] - d;
}

__global__ __launch_bounds__(256) void k_scan3(int* __restrict__ rowstart,
                                               int* __restrict__ cursor,
                                               const int* __restrict__ part,
                                               int N, int E)
{
    int i = blockIdx.x * 256 + threadIdx.x;
    if (i < N) {
        int v = rowstart[i] + part[blockIdx.x];
        rowstart[i] = v;
        cursor[i] = v;
    }
    if (i == 0) rowstart[N] = E;
}

__global__ __launch_bounds__(256) void k_scatter(const int* __restrict__ src,
                                                 const int* __restrict__ dst,
                                                 int* __restrict__ cursor,
                                                 int* __restrict__ esrc, int E)
{
    int e = blockIdx.x * 256 + threadIdx.x;
    if (e < E) {
        int pos = atomicAdd(&cursor[dst[e]], 1);
        esrc[pos] = src[e];
    }
}

// ---------------------------------------------------------------------------
// K3: CSR aggregation (R7 structure; inner loop unrolled x4 this round).
// ---------------------------------------------------------------------------
__global__ __launch_bounds__(256) void k_aggregate(
    const float* __restrict__ Ah, const u32* __restrict__ DB,
    const u32* __restrict__ Ehb,
    const int* __restrict__ rowstart, const int* __restrict__ esrc,
    float* __restrict__ hnew, float* __restrict__ gsum, float* __restrict__ gsq,
    int N)
{
    int t = threadIdx.x;
    int lane = t & 63;
    int wv = t >> 6;
    int nquads = (N + 3) >> 2;

    float lsum0 = 0.f, lsum1 = 0.f, lsq0 = 0.f, lsq1 = 0.f;
    for (int q = blockIdx.x; q < nquads; q += gridDim.x) {
        int n = q * 4 + wv;
        if (n < N) {
            u32 ehp = Ehb[(size_t)n * 64 + lane];
            float eh0 = bflo(ehp), eh1 = bfhi(ehp);
            float2 ahp = ((const float2*)Ah)[(size_t)n * 64 + lane];
            float num0 = 0.f, den0 = 0.f, num1 = 0.f, den1 = 0.f;
            int beg = rowstart[n], end = rowstart[n + 1];
            int k = beg;
            for (; k + 4 <= end; k += 4) {
                int s0 = esrc[k], s1 = esrc[k + 1], s2 = esrc[k + 2], s3 = esrc[k + 3];
                u32 dhA = DB[(size_t)s0 * 128 + lane];
                u32 bhA = DB[(size_t)s0 * 128 + 64 + lane];
                u32 dhB = DB[(size_t)s1 * 128 + lane];
                u32 bhB = DB[(size_t)s1 * 128 + 64 + lane];
                u32 dhC = DB[(size_t)s2 * 128 + lane];
                u32 bhC = DB[(size_t)s2 * 128 + 64 + lane];
                u32 dhD = DB[(size_t)s3 * 128 + lane];
                u32 bhD = DB[(size_t)s3 * 128 + 64 + lane];
                float sA0 = 1.f / (1.f + __expf(-(bflo(dhA) + eh0)));
                float sA1 = 1.f / (1.f + __expf(-(bfhi(dhA) + eh1)));
                float sB0 = 1.f / (1.f + __expf(-(bflo(dhB) + eh0)));
                float sB1 = 1.f / (1.f + __expf(-(bfhi(dhB) + eh1)));
                float sC0 = 1.f / (1.f + __expf(-(bflo(dhC) + eh0)));
                float sC1 = 1.f / (1.f + __expf(-(bfhi(dhC) + eh1)));
                float sD0 = 1.f / (1.f + __expf(-(bflo(dhD) + eh0)));
                float sD1 = 1.f / (1.f + __expf(-(bfhi(dhD) + eh1)));
                num0 = fmaf(sA0, bflo(bhA), num0); den0 += sA0;
                num1 = fmaf(sA1, bfhi(bhA), num1); den1 += sA1;
                num0 = fmaf(sB0, bflo(bhB), num0); den0 += sB0;
                num1 = fmaf(sB1, bfhi(bhB), num1); den1 += sB1;
                num0 = fmaf(sC0, bflo(bhC), num0); den0 += sC0;
                num1 = fmaf(sC1, bfhi(bhC), num1); den1 += sC1;
                num0 = fmaf(sD0, bflo(bhD), num0); den0 += sD0;
                num1 = fmaf(sD1, bfhi(bhD), num1); den1 += sD1;
            }
            for (; k < end; ++k) {
                int s0 = esrc[k];
                u32 dh0 = DB[(size_t)s0 * 128 + lane];
                u32 bh0 = DB[(size_t)s0 * 128 + 64 + lane];
                float sa0 = 1.f / (1.f + __expf(-(bflo(dh0) + eh0)));
                float sa1 = 1.f / (1.f + __expf(-(bfhi(dh0) + eh1)));
                num0 = fmaf(sa0, bflo(bh0), num0); den0 += sa0;
                num1 = fmaf(sa1, bfhi(bh0), num1); den1 += sa1;
            }
            float x0 = ahp.x + num0 / (den0 + GATE_EPS);
            float x1 = ahp.y + num1 / (den1 + GATE_EPS);
            ((float2*)hnew)[(size_t)n * 64 + lane] = make_float2(x0, x1);
            lsum0 += x0; lsq0 += x0 * x0;
            lsum1 += x1; lsq1 += x1 * x1;
        }
    }
    __shared__ float S0[256], S1[256], Q0[256], Q1[256];
    S0[t] = lsum0; S1[t] = lsum1; Q0[t] = lsq0; Q1[t] = lsq1;
    __syncthreads();
    if (t < 64) {
        float s0 = S0[t] + S0[t + 64] + S0[t + 128] + S0[t + 192];
        float s1 = S1[t] + S1[t + 64] + S1[t + 128] + S1[t + 192];
        float q0 = Q0[t] + Q0[t + 64] + Q0[t + 128] + Q0[t + 192];
        float q1 = Q1[t] + Q1[t + 64] + Q1[t + 128] + Q1[t + 192];
        atomicAdd(&gsum[2 * t],     s0);
        atomicAdd(&gsum[2 * t + 1], s1);
        atomicAdd(&gsq[2 * t],      q0);
        atomicAdd(&gsq[2 * t + 1],  q1);
    }
}

// ---------------------------------------------------------------------------
// K4: finalize BN stats (verbatim from passing rounds).
// ---------------------------------------------------------------------------
__global__ void bn_finalize(const float* __restrict__ gsum, const float* __restrict__ gsq,
                            const void* __restrict__ gamma, const void* __restrict__ beta,
                            float* __restrict__ scale, float* __restrict__ shift,
                            int N, const int* __restrict__ flagp)
{
    int c = threadIdx.x;
    int bf = *flagp;
    if (c < DIM) {
        float invn = 1.f / (float)N;
        float mean = gsum[c] * invn;
        float var  = fmaxf(gsq[c] * invn - mean * mean, 0.f);
        float g = loadF(gamma, c, bf);
        float b = loadF(beta, c, bf);
        float sc = rsqrtf(var + BN_EPS) * g;
        scale[c] = sc;
        shift[c] = b - mean * sc;
    }
}

// ---------------------------------------------------------------------------
// K5: y = relu(x*scale + shift), scalar store (verbatim from passing rounds).
// ---------------------------------------------------------------------------
__global__ __launch_bounds__(256) void bn_apply(
    const float* __restrict__ hnew, const float* __restrict__ scale,
    const float* __restrict__ shift, void* __restrict__ outh,
    int total, const int* __restrict__ flagp)
{
    __shared__ float s_sc[DIM], s_sh[DIM];
    int t = threadIdx.x;
    if (t < DIM) { s_sc[t] = scale[t]; s_sh[t] = shift[t]; }
    __syncthreads();
    int bf = *flagp;

    int idx = blockIdx.x * 256 + t;
    int stride = gridDim.x * 256;
    for (int i = idx; i < total; i += stride) {
        int c = i & 127;
        float x = fmaxf(0.f, hnew[i] * s_sc[c] + s_sh[c]);
        if (bf) ((u16*)outh)[i] = f2bf(x);
        else    ((float*)outh)[i] = x;
    }
}

// ---------------------------------------------------------------------------
// K6: copy e into d_out at element offset nd (verbatim from passing rounds).
// ---------------------------------------------------------------------------
__global__ __launch_bounds__(256) void copy_e(
    const void* __restrict__ e, void* __restrict__ dout,
    size_t nd, size_t ecount, const int* __restrict__ flagp)
{
    int bf = *flagp;
    size_t esz = bf ? 2 : 4;
    const uint4* s = (const uint4*)e;
    uint4* d = (uint4*)((char*)dout + nd * esz);
    size_t n16 = (ecount * esz) / 16;
    size_t idx = (size_t)blockIdx.x * 256 + threadIdx.x;
    size_t stride = (size_t)gridDim.x * 256;
    for (size_t i = idx; i < n16; i += stride) d[i] = s[i];
}

// ---------------------------------------------------------------------------
extern "C" void kernel_launch(void* const* d_in, const int* in_sizes, int n_in,
                              void* d_out, int out_size, void* d_ws, size_t ws_size,
                              hipStream_t stream)
{
    const void* h     = d_in[0];
    const void* e     = d_in[1];
    const int*  src   = (const int*)d_in[2];
    const int*  dst   = (const int*)d_in[3];
    const void* Wa    = d_in[4];
    const void* ba    = d_in[5];
    const void* Wb    = d_in[6];
    const void* bb    = d_in[7];
    const void* Wd    = d_in[8];
    const void* bd    = d_in[9];
    const void* We    = d_in[10];
    const void* be    = d_in[11];
    const void* gamma = d_in[12];
    const void* beta  = d_in[13];

    const int N = in_sizes[0] / DIM;        // 50000
    const int E = in_sizes[2];              // 800000
    const size_t nd = (size_t)N * DIM;
    const size_t ecount = (size_t)E * DIM;

    float* ws    = (float*)d_ws;
    float* Ah    = ws;                         // nd f32
    float* hnew  = ws + nd;                    // nd f32
    u32*   DB    = (u32*)(ws + 2 * nd);        // N*128 u32 (Dh|Bh bf16 pairs)
    u32*   Ehb   = (u32*)(ws + 3 * nd);        // N*64 u32 (Eh bf16 pairs)
    float* gsum  = ws + 3 * nd + nd / 2;       // 128
    float* gsq   = gsum + DIM;                 // 128
    float* scale = gsum + 2 * DIM;             // 128
    float* shift = gsum + 3 * DIM;             // 128
    u32*   Wt32  = (u32*)(gsum + 4 * DIM + 64);// 4*8192 u32 = 128 KB
    int*   flag  = (int*)(gsum + 4 * DIM);     // [0]=dtype, [1]=mfma-ok, [2]=always0
    int*   deg      = (int*)(Wt32 + 4 * 8192); // N
    int*   rowstart = deg + N;                 // N+1
    int*   cursor   = rowstart + N + 1;        // N
    int*   part     = cursor + N;              // 256
    int*   esrc     = part + 256;              // E

    // zero BN stats + flag area FIRST (flag[2] must be 0 deterministically),
    // then detect_dtype writes flag[0].
    hipMemsetAsync(gsum, 0, (4 * DIM + 64) * sizeof(float), stream);
    hipMemsetAsync(deg, 0, (size_t)N * sizeof(int), stream);

    detect_dtype<<<1, 64, 0, stream>>>(h, flag);

    const int nbE = (E + 255) / 256;
    const int nbN = (N + 255) / 256;

    k_hist<<<nbE, 256, 0, stream>>>(dst, deg, E);
    k_scan1<<<nbN, 256, 0, stream>>>(deg, rowstart, part, N);
    k_scan2<<<1, 256, 0, stream>>>(part, nbN);
    k_scan3<<<nbN, 256, 0, stream>>>(rowstart, cursor, part, N, E);
    k_scatter<<<nbE, 256, 0, stream>>>(src, dst, cursor, esrc, E);

#if HAVE_MFMA16
    k_transposeW<<<4, 256, 0, stream>>>((const u16*)Wa, (const u16*)Wb,
                                        (const u16*)Wd, (const u16*)We, Wt32);

    dim3 gm((N + 63) / 64, 8);
    mfma16_proj<<<gm, 256, 0, stream>>>((const u16*)h, (const u16*)Wt32,
                                        (const u16*)ba, (const u16*)bb,
                                        (const u16*)bd, (const u16*)be,
                                        Ah, (u16*)DB, (u16*)Ehb, N);

    k_verify<<<1, 256, 0, stream>>>((const u16*)h,
                                    (const u16*)Wa, (const u16*)Wb,
                                    (const u16*)Wd, (const u16*)We,
                                    (const u16*)ba, (const u16*)bb,
                                    (const u16*)bd, (const u16*)be,
                                    Ah, (const u16*)DB, (const u16*)Ehb,
                                    N, flag + 1);
    const int* okp = flag + 1;
#else
    const int* okp = flag + 2;   // always 0 -> repair always runs
#endif

    dim3 gr((N + 63) / 64, 4);
    k_repair<<<gr, 256, 0, stream>>>(h, Wa, ba, Wb, bb, Wd, bd, We, be,
                                     Ah, DB, Ehb, N, flag, okp);

    k_aggregate<<<2048, 256, 0, stream>>>(Ah, DB, Ehb, rowstart, esrc,
                                          hnew, gsum, gsq, N);

    bn_finalize<<<1, 128, 0, stream>>>(gsum, gsq, gamma, beta, scale, shift, N, flag);

    bn_apply<<<2048, 256, 0, stream>>>(hnew, scale, shift, d_out, (int)nd, flag);

    copy_e<<<4096, 256, 0, stream>>>(e, d_out, nd, ecount, flag);
}